// Round 12
// baseline (78.445 us; speedup 1.0000x reference)
//
#include <hip/hip_runtime.h>

// CPAMDec — R12: R11 + bank-conflict-free padded subtile (lg stride 272) +
// full-depth staging issue (16 float4 in flight). Numerics identical to R7-R11.
//   energy[px][kk] = sum_c x_bf[px][c] * wqk_bf[c][kk] (+bqk)
//   out[c][px]     = fs * sum_kk vT_bf[c][kk] * attn_bf[kk][px] + x[c][px]
// Frag layouts (mfma_f32_16x16x32_bf16), HW-verified R5/R6:
//   A[m][k]: lane l -> m=l&15, k=8*(l>>4)+j ; B[k][n]: lane l -> n=l&15, k=8*(l>>4)+j
//   D[m][n]: lane l -> n=l&15, m=4*(l>>4)+r
// xl padded subtile: elem(c,px) = (c>>5)*1088 + ((c>>3)&3)*272 + ((c>>2)&1)*128
//                              + (c&3)*16 + ((px>>4)&1)*64 + (px&15)
// ws: wqkf bf16[N][32*512] @0 (256K) | vtf bf16[N][32*512] @256K | bqk f32[256] @512K

#define N_  8
#define C_  512
#define HW_ 4096
#define K_  32

typedef __attribute__((ext_vector_type(8))) short bf16x8;
typedef __attribute__((ext_vector_type(4))) float f32x4;
typedef __attribute__((ext_vector_type(2))) int i32x2;
typedef __attribute__((ext_vector_type(4))) int i32x4;

__device__ __forceinline__ unsigned short f2b(float f) {
    union { float f; unsigned u; } v; v.f = f;
    unsigned r = v.u + 0x7FFFu + ((v.u >> 16) & 1u);   // RNE
    return (unsigned short)(r >> 16);
}

// wqk frag slot: wqk[kk][c] -> elem ((cs*2+kt)*64 + g*16 + (kk&15))*8 + j
__device__ __forceinline__ int wqk_idx(int kk, int c) {
    return ((((c >> 5) * 2 + (kk >> 4)) * 64 + ((c >> 3) & 3) * 16 + (kk & 15)) << 3) + (c & 7);
}

__global__ __launch_bounds__(256) void prep_kernel(
    const float* __restrict__ y, const float* __restrict__ wq, const float* __restrict__ bq,
    const float* __restrict__ wk, const float* __restrict__ bk,
    const float* __restrict__ wv, const float* __restrict__ bv,
    unsigned short* __restrict__ wqkf, float* __restrict__ bqk, unsigned short* __restrict__ vtf)
{
    const int bid = blockIdx.x;
    const int t = threadIdx.x;

    if (bid < 256) {
        // role A: v rows -> vtf frags. block = (n, ct of 16 c).
        __shared__ float vred[3][4][16][8];              // 6 KB
        const int n   = bid >> 5;
        const int ct  = bid & 31;
        const int cl  = t & 15;
        const int kko = (t >> 4) & 3;
        const int jq4 = t >> 6;
        const int c   = ct * 16 + cl;

        const float* yb  = y  + ((size_t)n * K_ + kko * 8) * C_ + jq4 * 128;
        const float* wvb = wv + (size_t)c * C_ + jq4 * 128;
        float acc[8] = {0,0,0,0,0,0,0,0};
        #pragma unroll 4
        for (int jj = 0; jj < 32; ++jj) {
            float4 w4 = *(const float4*)(wvb + jj * 4);
            #pragma unroll
            for (int u = 0; u < 8; ++u) {
                float4 y4 = *(const float4*)(yb + (size_t)u * C_ + jj * 4);
                acc[u] += y4.x * w4.x + y4.y * w4.y + y4.z * w4.z + y4.w * w4.w;
            }
        }
        if (jq4 > 0) {
            #pragma unroll
            for (int u = 0; u < 8; ++u) vred[jq4 - 1][kko][cl][u] = acc[u];
        }
        __syncthreads();
        if (jq4 == 0) {
            const float bvc = bv[c];
            unsigned short o[8];
            #pragma unroll
            for (int u = 0; u < 8; ++u) {
                float s = acc[u] + vred[0][kko][cl][u] + vred[1][kko][cl][u]
                        + vred[2][kko][cl][u] + bvc;
                o[u] = f2b(s);
            }
            i32x4 pk = { (int)(o[0] | ((unsigned)o[1] << 16)), (int)(o[2] | ((unsigned)o[3] << 16)),
                         (int)(o[4] | ((unsigned)o[5] << 16)), (int)(o[6] | ((unsigned)o[7] << 16)) };
            *(i32x4*)(vtf + (size_t)n * (K_ * C_) + (size_t)((ct * 64 + kko * 16 + cl) * 8)) = pk;
        }
    } else {
        // role B: krow -> bqk, wqk frags. block = (n, kk)
        __shared__ __align__(16) float kp[2][128];
        __shared__ __align__(16) float kr[128];
        const int b = bid - 256;
        const int n = b >> 5, kk = b & 31;
        const int o = t & 127, half = t >> 7;

        const float* yb  = y  + ((size_t)n * K_ + kk) * C_ + half * 256;
        const float* wkb = wk + (size_t)o * C_ + half * 256;
        float a = 0.f;
        #pragma unroll 4
        for (int jq = 0; jq < 64; ++jq) {
            float4 w4 = *(const float4*)(wkb + jq * 4);
            float4 y4 = *(const float4*)(yb + jq * 4);
            a += y4.x * w4.x + y4.y * w4.y + y4.z * w4.z + y4.w * w4.w;
        }
        kp[half][o] = a;
        __syncthreads();
        if (t < 128) kr[t] = kp[0][t] + kp[1][t] + bk[t];
        __syncthreads();
        if (t < 64) {
            float s = kr[t] * bq[t] + kr[t + 64] * bq[t + 64];
            #pragma unroll
            for (int d = 32; d > 0; d >>= 1) s += __shfl_down(s, d);
            if (t == 0) bqk[n * K_ + kk] = s;
        }
        const int c1 = t, c2 = t + 256;
        float s1 = 0.f, s2 = 0.f;
        for (int oq = 0; oq < 32; ++oq) {
            float4 k4 = *(const float4*)(&kr[oq * 4]);
            const float* wq0 = wq + (size_t)(oq * 4) * C_;
            s1 += k4.x * wq0[c1] + k4.y * wq0[C_ + c1] + k4.z * wq0[2*C_ + c1] + k4.w * wq0[3*C_ + c1];
            s2 += k4.x * wq0[c2] + k4.y * wq0[C_ + c2] + k4.z * wq0[2*C_ + c2] + k4.w * wq0[3*C_ + c2];
        }
        unsigned short* wqf_n = wqkf + (size_t)n * (K_ * C_);
        wqf_n[wqk_idx(kk, c1)] = f2b(s1);
        wqf_n[wqk_idx(kk, c2)] = f2b(s2);
    }
}

__global__ __launch_bounds__(256, 4) void main_kernel(
    const float* __restrict__ x, const unsigned short* __restrict__ wqkf,
    const unsigned short* __restrict__ vtf, const float* __restrict__ bqk,
    const float* __restrict__ scale, float* __restrict__ out)
{
    __shared__ __align__(16) unsigned short xl[17408];   // 34 KB padded bf16 x-tile
    __shared__ float e_lds[32][33];                       // 4.2 KB

    // XCD swizzle: 128 consecutive tiles (= one image n) per XCD
    const int bid = (blockIdx.x & 7) * 128 + (blockIdx.x >> 3);
    const int n  = bid >> 7;
    const int p0 = (bid & 127) * 32;
    const int t  = threadIdx.x;
    const int w  = t >> 6, l = t & 63;
    const int l15 = l & 15, lg = l >> 4;
    const float* xg = x + (size_t)n * C_ * HW_;
    float* og = out + (size_t)n * C_ * HW_;

    // ---- Phase 0: stage x-tile -> LDS bf16 (padded subtile), 16 loads in flight ----
    {
        const float* xp0 = xg + p0;
        const int px4 = (t & 7) * 4;           // 4 consecutive px
        const int crow = t >> 3;               // 0..31
        const int pxh = ((px4 >> 4) & 1) * 64 + (px4 & 15);
        const int crowpart = ((crow >> 3) & 3) * 272 + ((crow >> 2) & 1) * 128
                           + (crow & 3) * 16 + pxh;

        float4 ra[16];
        #pragma unroll
        for (int b = 0; b < 4; ++b)
            #pragma unroll
            for (int u = 0; u < 4; ++u)
                ra[b * 4 + u] = *(const float4*)(xp0 + (size_t)(b * 128 + u * 32 + crow) * HW_ + px4);
        #pragma unroll
        for (int b = 0; b < 4; ++b)
            #pragma unroll
            for (int u = 0; u < 4; ++u) {
                const float4 r = ra[b * 4 + u];
                const int elem = (b * 4 + u) * 1088 + crowpart;
                i32x2 pk = { (int)(f2b(r.x) | ((unsigned)f2b(r.y) << 16)),
                             (int)(f2b(r.z) | ((unsigned)f2b(r.w) << 16)) };
                *(i32x2*)(xl + elem) = pk;
            }
    }
    __syncthreads();

    // ---- Phase 1: energy MFMA; A from padded LDS (2-way max conflicts) ----
    {
        const int pt = w & 1, kt = w >> 1;
        const unsigned short* wqf = wqkf + (size_t)n * (K_ * C_);
        bf16x8 bcur = *(const bf16x8*)(wqf + ((size_t)kt * 64 + l) * 8);

        f32x4 acc = {0.f, 0.f, 0.f, 0.f};
        for (int cs = 0; cs < 16; ++cs) {
            bf16x8 bnext;
            if (cs < 15) bnext = *(const bf16x8*)(wqf + ((size_t)((cs + 1) * 2 + kt) * 64 + l) * 8);
            const unsigned short* xp = xl + cs * 1088 + lg * 272 + pt * 64 + l15;
            const unsigned e0 = xp[0],   e1 = xp[16],  e2 = xp[32],  e3 = xp[48];
            const unsigned e4 = xp[128], e5 = xp[144], e6 = xp[160], e7 = xp[176];
            union { unsigned u[4]; bf16x8 v; } af;
            af.u[0] = e0 | (e1 << 16);  af.u[1] = e2 | (e3 << 16);
            af.u[2] = e4 | (e5 << 16);  af.u[3] = e6 | (e7 << 16);
            acc = __builtin_amdgcn_mfma_f32_16x16x32_bf16(af.v, bcur, acc, 0, 0, 0);
            bcur = bnext;
        }
        const float bq_ = bqk[n * K_ + kt * 16 + l15];
        #pragma unroll
        for (int r = 0; r < 4; ++r)
            e_lds[pt * 16 + lg * 4 + r][kt * 16 + l15] = acc[r] + bq_;
    }
    __syncthreads();

    // ---- Phase 2: per-lane softmax for px = (w&1)*16+l15; PV B-frag in regs ----
    bf16x8 paf;
    {
        const float* er = e_lds[(w & 1) * 16 + l15];
        float e[32];
        #pragma unroll
        for (int k = 0; k < 32; ++k) e[k] = er[k];
        float mx = e[0];
        #pragma unroll
        for (int k = 1; k < 32; ++k) mx = fmaxf(mx, e[k]);
        float s = 0.f;
        #pragma unroll
        for (int k = 0; k < 32; ++k) { e[k] = __expf(e[k] - mx); s += e[k]; }
        const float inv = 1.f / s;
        #pragma unroll
        for (int j = 0; j < 8; ++j) paf[j] = (short)f2b(e[8 * lg + j] * inv);
    }

    // ---- Phase 3: PV MFMA + residual, depth-2 pipelined, direct stores ----
    {
        const int pxt = w & 1, mh = w >> 1;            // mh 0..1 -> 256 c each
        const unsigned short* vtfn = vtf + (size_t)n * (K_ * C_);
        const float fs = scale[0];
        const int px = p0 + pxt * 16 + l15;

        const int mt0 = mh * 16;
        bf16x8 va = *(const bf16x8*)(vtfn + ((size_t)mt0 * 64 + l) * 8);
        bf16x8 vb = *(const bf16x8*)(vtfn + ((size_t)(mt0 + 1) * 64 + l) * 8);
        float xa[4], xb[4];
        {
            const int ca = mt0 * 16 + lg * 4, cb = (mt0 + 1) * 16 + lg * 4;
            #pragma unroll
            for (int r = 0; r < 4; ++r) xa[r] = xg[(size_t)(ca + r) * HW_ + px];
            #pragma unroll
            for (int r = 0; r < 4; ++r) xb[r] = xg[(size_t)(cb + r) * HW_ + px];
        }

        for (int mi = 0; mi < 16; ++mi) {
            const int mt = mt0 + mi;
            bf16x8 vc;
            float xc[4];
            if (mi < 14) {
                vc = *(const bf16x8*)(vtfn + ((size_t)(mt + 2) * 64 + l) * 8);
                const int cn = (mt + 2) * 16 + lg * 4;
                #pragma unroll
                for (int r = 0; r < 4; ++r) xc[r] = xg[(size_t)(cn + r) * HW_ + px];
            }
            f32x4 d = __builtin_amdgcn_mfma_f32_16x16x32_bf16(va, paf, (f32x4){0.f,0.f,0.f,0.f}, 0, 0, 0);
            const int cc = mt * 16 + lg * 4;
            og[(size_t)cc * HW_ + px]       = fs * d[0] + xa[0];
            og[(size_t)(cc+1) * HW_ + px]   = fs * d[1] + xa[1];
            og[(size_t)(cc+2) * HW_ + px]   = fs * d[2] + xa[2];
            og[(size_t)(cc+3) * HW_ + px]   = fs * d[3] + xa[3];
            va = vb; vb = vc;
            #pragma unroll
            for (int r = 0; r < 4; ++r) { xa[r] = xb[r]; xb[r] = xc[r]; }
        }
    }
}

extern "C" void kernel_launch(void* const* d_in, const int* in_sizes, int n_in,
                              void* d_out, int out_size, void* d_ws, size_t ws_size,
                              hipStream_t stream) {
    const float* x     = (const float*)d_in[0];
    const float* y     = (const float*)d_in[1];
    const float* wq    = (const float*)d_in[2];
    const float* bq    = (const float*)d_in[3];
    const float* wk    = (const float*)d_in[4];
    const float* bk    = (const float*)d_in[5];
    const float* wv    = (const float*)d_in[6];
    const float* bv    = (const float*)d_in[7];
    const float* scale = (const float*)d_in[8];

    unsigned short* wqkf = (unsigned short*)d_ws;                       // 256 KB
    unsigned short* vtf  = wqkf + (size_t)N_ * K_ * C_;                 // 256 KB
    float* bqk = (float*)((char*)d_ws + 524288);                        // 1 KB

    prep_kernel<<<512, 256, 0, stream>>>(y, wq, bq, wk, bk, wv, bv, wqkf, bqk, vtf);
    main_kernel<<<1024, 256, 0, stream>>>(x, wqkf, vtf, bqk, scale, (float*)d_out);
}

// Round 13
// 67.301 us; speedup vs baseline: 1.1656x; 1.1656x over previous
//
#include <hip/hip_runtime.h>

// CPAMDec — R13: R11 staging (2-batch) + R12 padded subtile + full-line writes:
// each wave owns BOTH px-halves of its c-quarter (paf0/paf1 per lane) so every
// 128B out-line is written by one wave back-to-back. Numerics identical to R7+.
//   energy[px][kk] = sum_c x_bf[px][c] * wqk_bf[c][kk] (+bqk)
//   out[c][px]     = fs * sum_kk vT_bf[c][kk] * attn_bf[kk][px] + x[c][px]
// Frag layouts (mfma_f32_16x16x32_bf16), HW-verified R5/R6:
//   A[m][k]: lane l -> m=l&15, k=8*(l>>4)+j ; B[k][n]: lane l -> n=l&15, k=8*(l>>4)+j
//   D[m][n]: lane l -> n=l&15, m=4*(l>>4)+r
// xl padded subtile: elem(c,px) = (c>>5)*1088 + ((c>>3)&3)*272 + ((c>>2)&1)*128
//                              + (c&3)*16 + ((px>>4)&1)*64 + (px&15)
// ws: wqkf bf16[N][32*512] @0 (256K) | vtf bf16[N][32*512] @256K | bqk f32[256] @512K

#define N_  8
#define C_  512
#define HW_ 4096
#define K_  32

typedef __attribute__((ext_vector_type(8))) short bf16x8;
typedef __attribute__((ext_vector_type(4))) float f32x4;
typedef __attribute__((ext_vector_type(2))) int i32x2;
typedef __attribute__((ext_vector_type(4))) int i32x4;

__device__ __forceinline__ unsigned short f2b(float f) {
    union { float f; unsigned u; } v; v.f = f;
    unsigned r = v.u + 0x7FFFu + ((v.u >> 16) & 1u);   // RNE
    return (unsigned short)(r >> 16);
}

// wqk frag slot: wqk[kk][c] -> elem ((cs*2+kt)*64 + g*16 + (kk&15))*8 + j
__device__ __forceinline__ int wqk_idx(int kk, int c) {
    return ((((c >> 5) * 2 + (kk >> 4)) * 64 + ((c >> 3) & 3) * 16 + (kk & 15)) << 3) + (c & 7);
}

__global__ __launch_bounds__(256) void prep_kernel(
    const float* __restrict__ y, const float* __restrict__ wq, const float* __restrict__ bq,
    const float* __restrict__ wk, const float* __restrict__ bk,
    const float* __restrict__ wv, const float* __restrict__ bv,
    unsigned short* __restrict__ wqkf, float* __restrict__ bqk, unsigned short* __restrict__ vtf)
{
    const int bid = blockIdx.x;
    const int t = threadIdx.x;

    if (bid < 256) {
        // role A: v rows -> vtf frags. block = (n, ct of 16 c).
        __shared__ float vred[3][4][16][8];              // 6 KB
        const int n   = bid >> 5;
        const int ct  = bid & 31;
        const int cl  = t & 15;
        const int kko = (t >> 4) & 3;
        const int jq4 = t >> 6;
        const int c   = ct * 16 + cl;

        const float* yb  = y  + ((size_t)n * K_ + kko * 8) * C_ + jq4 * 128;
        const float* wvb = wv + (size_t)c * C_ + jq4 * 128;
        float acc[8] = {0,0,0,0,0,0,0,0};
        #pragma unroll 4
        for (int jj = 0; jj < 32; ++jj) {
            float4 w4 = *(const float4*)(wvb + jj * 4);
            #pragma unroll
            for (int u = 0; u < 8; ++u) {
                float4 y4 = *(const float4*)(yb + (size_t)u * C_ + jj * 4);
                acc[u] += y4.x * w4.x + y4.y * w4.y + y4.z * w4.z + y4.w * w4.w;
            }
        }
        if (jq4 > 0) {
            #pragma unroll
            for (int u = 0; u < 8; ++u) vred[jq4 - 1][kko][cl][u] = acc[u];
        }
        __syncthreads();
        if (jq4 == 0) {
            const float bvc = bv[c];
            unsigned short o[8];
            #pragma unroll
            for (int u = 0; u < 8; ++u) {
                float s = acc[u] + vred[0][kko][cl][u] + vred[1][kko][cl][u]
                        + vred[2][kko][cl][u] + bvc;
                o[u] = f2b(s);
            }
            i32x4 pk = { (int)(o[0] | ((unsigned)o[1] << 16)), (int)(o[2] | ((unsigned)o[3] << 16)),
                         (int)(o[4] | ((unsigned)o[5] << 16)), (int)(o[6] | ((unsigned)o[7] << 16)) };
            *(i32x4*)(vtf + (size_t)n * (K_ * C_) + (size_t)((ct * 64 + kko * 16 + cl) * 8)) = pk;
        }
    } else {
        // role B: krow -> bqk, wqk frags. block = (n, kk)
        __shared__ __align__(16) float kp[2][128];
        __shared__ __align__(16) float kr[128];
        const int b = bid - 256;
        const int n = b >> 5, kk = b & 31;
        const int o = t & 127, half = t >> 7;

        const float* yb  = y  + ((size_t)n * K_ + kk) * C_ + half * 256;
        const float* wkb = wk + (size_t)o * C_ + half * 256;
        float a = 0.f;
        #pragma unroll 4
        for (int jq = 0; jq < 64; ++jq) {
            float4 w4 = *(const float4*)(wkb + jq * 4);
            float4 y4 = *(const float4*)(yb + jq * 4);
            a += y4.x * w4.x + y4.y * w4.y + y4.z * w4.z + y4.w * w4.w;
        }
        kp[half][o] = a;
        __syncthreads();
        if (t < 128) kr[t] = kp[0][t] + kp[1][t] + bk[t];
        __syncthreads();
        if (t < 64) {
            float s = kr[t] * bq[t] + kr[t + 64] * bq[t + 64];
            #pragma unroll
            for (int d = 32; d > 0; d >>= 1) s += __shfl_down(s, d);
            if (t == 0) bqk[n * K_ + kk] = s;
        }
        const int c1 = t, c2 = t + 256;
        float s1 = 0.f, s2 = 0.f;
        for (int oq = 0; oq < 32; ++oq) {
            float4 k4 = *(const float4*)(&kr[oq * 4]);
            const float* wq0 = wq + (size_t)(oq * 4) * C_;
            s1 += k4.x * wq0[c1] + k4.y * wq0[C_ + c1] + k4.z * wq0[2*C_ + c1] + k4.w * wq0[3*C_ + c1];
            s2 += k4.x * wq0[c2] + k4.y * wq0[C_ + c2] + k4.z * wq0[2*C_ + c2] + k4.w * wq0[3*C_ + c2];
        }
        unsigned short* wqf_n = wqkf + (size_t)n * (K_ * C_);
        wqf_n[wqk_idx(kk, c1)] = f2b(s1);
        wqf_n[wqk_idx(kk, c2)] = f2b(s2);
    }
}

__global__ __launch_bounds__(256) void main_kernel(
    const float* __restrict__ x, const unsigned short* __restrict__ wqkf,
    const unsigned short* __restrict__ vtf, const float* __restrict__ bqk,
    const float* __restrict__ scale, float* __restrict__ out)
{
    __shared__ __align__(16) unsigned short xl[17408];   // 34 KB padded bf16 x-tile
    __shared__ float e_lds[32][33];                       // 4.2 KB

    // XCD swizzle: 128 consecutive tiles (= one image n) per XCD
    const int bid = (blockIdx.x & 7) * 128 + (blockIdx.x >> 3);
    const int n  = bid >> 7;
    const int p0 = (bid & 127) * 32;
    const int t  = threadIdx.x;
    const int w  = t >> 6, l = t & 63;
    const int l15 = l & 15, lg = l >> 4;
    const float* xg = x + (size_t)n * C_ * HW_;
    float* og = out + (size_t)n * C_ * HW_;

    // ---- Phase 0: stage x-tile -> LDS bf16 (padded subtile), 2-batch pipeline ----
    {
        const float* xp0 = xg + p0;
        const int px4 = (t & 7) * 4;           // 4 consecutive px
        const int crow = t >> 3;               // 0..31
        const int pxh = ((px4 >> 4) & 1) * 64 + (px4 & 15);
        const int crowpart = ((crow >> 3) & 3) * 272 + ((crow >> 2) & 1) * 128
                           + (crow & 3) * 16 + pxh;

        float4 ra[4], rb[4];
        #pragma unroll
        for (int u = 0; u < 4; ++u)
            ra[u] = *(const float4*)(xp0 + (size_t)(u * 32 + crow) * HW_ + px4);
        for (int b = 0; b < 4; ++b) {
            if (b < 3) {
                #pragma unroll
                for (int u = 0; u < 4; ++u)
                    rb[u] = *(const float4*)(xp0 + (size_t)((b + 1) * 128 + u * 32 + crow) * HW_ + px4);
            }
            #pragma unroll
            for (int u = 0; u < 4; ++u) {
                const float4 r = ra[u];
                const int elem = (b * 4 + u) * 1088 + crowpart;
                i32x2 pk = { (int)(f2b(r.x) | ((unsigned)f2b(r.y) << 16)),
                             (int)(f2b(r.z) | ((unsigned)f2b(r.w) << 16)) };
                *(i32x2*)(xl + elem) = pk;
            }
            #pragma unroll
            for (int u = 0; u < 4; ++u) ra[u] = rb[u];
        }
    }
    __syncthreads();

    // ---- Phase 1: energy MFMA; A from padded LDS (2-way max conflicts) ----
    {
        const int pt = w & 1, kt = w >> 1;
        const unsigned short* wqf = wqkf + (size_t)n * (K_ * C_);
        bf16x8 bcur = *(const bf16x8*)(wqf + ((size_t)kt * 64 + l) * 8);

        f32x4 acc = {0.f, 0.f, 0.f, 0.f};
        for (int cs = 0; cs < 16; ++cs) {
            bf16x8 bnext;
            if (cs < 15) bnext = *(const bf16x8*)(wqf + ((size_t)((cs + 1) * 2 + kt) * 64 + l) * 8);
            const unsigned short* xp = xl + cs * 1088 + lg * 272 + pt * 64 + l15;
            const unsigned e0 = xp[0],   e1 = xp[16],  e2 = xp[32],  e3 = xp[48];
            const unsigned e4 = xp[128], e5 = xp[144], e6 = xp[160], e7 = xp[176];
            union { unsigned u[4]; bf16x8 v; } af;
            af.u[0] = e0 | (e1 << 16);  af.u[1] = e2 | (e3 << 16);
            af.u[2] = e4 | (e5 << 16);  af.u[3] = e6 | (e7 << 16);
            acc = __builtin_amdgcn_mfma_f32_16x16x32_bf16(af.v, bcur, acc, 0, 0, 0);
            bcur = bnext;
        }
        const float bq_ = bqk[n * K_ + kt * 16 + l15];
        #pragma unroll
        for (int r = 0; r < 4; ++r)
            e_lds[pt * 16 + lg * 4 + r][kt * 16 + l15] = acc[r] + bq_;
    }
    __syncthreads();

    // ---- Phase 2: per-lane softmax for BOTH px rows (l15 and 16+l15) ----
    bf16x8 paf0, paf1;
    {
        const float* er0 = e_lds[l15];
        const float* er1 = e_lds[16 + l15];
        float e0[32], e1[32];
        #pragma unroll
        for (int k = 0; k < 32; ++k) { e0[k] = er0[k]; e1[k] = er1[k]; }
        float m0 = e0[0], m1 = e1[0];
        #pragma unroll
        for (int k = 1; k < 32; ++k) { m0 = fmaxf(m0, e0[k]); m1 = fmaxf(m1, e1[k]); }
        float s0 = 0.f, s1 = 0.f;
        #pragma unroll
        for (int k = 0; k < 32; ++k) {
            e0[k] = __expf(e0[k] - m0); s0 += e0[k];
            e1[k] = __expf(e1[k] - m1); s1 += e1[k];
        }
        const float i0 = 1.f / s0, i1 = 1.f / s1;
        #pragma unroll
        for (int j = 0; j < 8; ++j) {
            paf0[j] = (short)f2b(e0[8 * lg + j] * i0);
            paf1[j] = (short)f2b(e1[8 * lg + j] * i1);
        }
    }

    // ---- Phase 3: PV MFMA, wave owns c-quarter + BOTH px halves (full-line writes) ----
    {
        const int mh = w;                               // 0..3 -> 128 c each
        const unsigned short* vtfn = vtf + (size_t)n * (K_ * C_);
        const float fs = scale[0];
        const int pxa = p0 + l15, pxb = p0 + 16 + l15;

        const int mt0 = mh * 8;
        bf16x8 vcur = *(const bf16x8*)(vtfn + ((size_t)mt0 * 64 + l) * 8);
        float xa0[4], xa1[4];
        {
            const int c0 = mt0 * 16 + lg * 4;
            #pragma unroll
            for (int r = 0; r < 4; ++r) {
                xa0[r] = xg[(size_t)(c0 + r) * HW_ + pxa];
                xa1[r] = xg[(size_t)(c0 + r) * HW_ + pxb];
            }
        }

        for (int mi = 0; mi < 8; ++mi) {
            const int mt = mt0 + mi;
            bf16x8 vnext;
            float xn0[4], xn1[4];
            if (mi < 7) {
                vnext = *(const bf16x8*)(vtfn + ((size_t)(mt + 1) * 64 + l) * 8);
                const int cn = (mt + 1) * 16 + lg * 4;
                #pragma unroll
                for (int r = 0; r < 4; ++r) {
                    xn0[r] = xg[(size_t)(cn + r) * HW_ + pxa];
                    xn1[r] = xg[(size_t)(cn + r) * HW_ + pxb];
                }
            }
            f32x4 d0 = __builtin_amdgcn_mfma_f32_16x16x32_bf16(vcur, paf0, (f32x4){0.f,0.f,0.f,0.f}, 0, 0, 0);
            f32x4 d1 = __builtin_amdgcn_mfma_f32_16x16x32_bf16(vcur, paf1, (f32x4){0.f,0.f,0.f,0.f}, 0, 0, 0);
            const int cc = mt * 16 + lg * 4;
            #pragma unroll
            for (int r = 0; r < 4; ++r) {
                og[(size_t)(cc + r) * HW_ + pxa] = fs * d0[r] + xa0[r];
                og[(size_t)(cc + r) * HW_ + pxb] = fs * d1[r] + xa1[r];
            }
            vcur = vnext;
            #pragma unroll
            for (int r = 0; r < 4; ++r) { xa0[r] = xn0[r]; xa1[r] = xn1[r]; }
        }
    }
}

extern "C" void kernel_launch(void* const* d_in, const int* in_sizes, int n_in,
                              void* d_out, int out_size, void* d_ws, size_t ws_size,
                              hipStream_t stream) {
    const float* x     = (const float*)d_in[0];
    const float* y     = (const float*)d_in[1];
    const float* wq    = (const float*)d_in[2];
    const float* bq    = (const float*)d_in[3];
    const float* wk    = (const float*)d_in[4];
    const float* bk    = (const float*)d_in[5];
    const float* wv    = (const float*)d_in[6];
    const float* bv    = (const float*)d_in[7];
    const float* scale = (const float*)d_in[8];

    unsigned short* wqkf = (unsigned short*)d_ws;                       // 256 KB
    unsigned short* vtf  = wqkf + (size_t)N_ * K_ * C_;                 // 256 KB
    float* bqk = (float*)((char*)d_ws + 524288);                        // 1 KB

    prep_kernel<<<512, 256, 0, stream>>>(y, wq, bq, wk, bk, wv, bv, wqkf, bqk, vtf);
    main_kernel<<<1024, 256, 0, stream>>>(x, wqkf, vtf, bqk, scale, (float*)d_out);
}

// Round 14
// 56.949 us; speedup vs baseline: 1.3775x; 1.1818x over previous
//
#include <hip/hip_runtime.h>

// CPAMDec — R14: R13 + residual read from staged LDS tile (kills phase-3 L2
// latency chain; residual is bf16-rounded, absmax budget ok) + depth-2 prefetch
// of B-frags (phase 1) and vtf frags (phase 3).
//   energy[px][kk] = sum_c x_bf[px][c] * wqk_bf[c][kk] (+bqk)
//   out[c][px]     = fs * sum_kk vT_bf[c][kk] * attn_bf[kk][px] + x_bf[c][px]
// Frag layouts (mfma_f32_16x16x32_bf16), HW-verified R5/R6:
//   A[m][k]: lane l -> m=l&15, k=8*(l>>4)+j ; B[k][n]: lane l -> n=l&15, k=8*(l>>4)+j
//   D[m][n]: lane l -> n=l&15, m=4*(l>>4)+r
// xl padded subtile: elem(c,px) = (c>>5)*1088 + ((c>>3)&3)*272 + ((c>>2)&1)*128
//                              + (c&3)*16 + ((px>>4)&1)*64 + (px&15)
// ws: wqkf bf16[N][32*512] @0 (256K) | vtf bf16[N][32*512] @256K | bqk f32[256] @512K

#define N_  8
#define C_  512
#define HW_ 4096
#define K_  32

typedef __attribute__((ext_vector_type(8))) short bf16x8;
typedef __attribute__((ext_vector_type(4))) float f32x4;
typedef __attribute__((ext_vector_type(2))) int i32x2;
typedef __attribute__((ext_vector_type(4))) int i32x4;

__device__ __forceinline__ unsigned short f2b(float f) {
    union { float f; unsigned u; } v; v.f = f;
    unsigned r = v.u + 0x7FFFu + ((v.u >> 16) & 1u);   // RNE
    return (unsigned short)(r >> 16);
}
__device__ __forceinline__ float b2f(unsigned short h) {
    union { unsigned u; float f; } v; v.u = ((unsigned)h) << 16; return v.f;
}

// wqk frag slot: wqk[kk][c] -> elem ((cs*2+kt)*64 + g*16 + (kk&15))*8 + j
__device__ __forceinline__ int wqk_idx(int kk, int c) {
    return ((((c >> 5) * 2 + (kk >> 4)) * 64 + ((c >> 3) & 3) * 16 + (kk & 15)) << 3) + (c & 7);
}

__global__ __launch_bounds__(256) void prep_kernel(
    const float* __restrict__ y, const float* __restrict__ wq, const float* __restrict__ bq,
    const float* __restrict__ wk, const float* __restrict__ bk,
    const float* __restrict__ wv, const float* __restrict__ bv,
    unsigned short* __restrict__ wqkf, float* __restrict__ bqk, unsigned short* __restrict__ vtf)
{
    const int bid = blockIdx.x;
    const int t = threadIdx.x;

    if (bid < 256) {
        // role A: v rows -> vtf frags. block = (n, ct of 16 c).
        __shared__ float vred[3][4][16][8];              // 6 KB
        const int n   = bid >> 5;
        const int ct  = bid & 31;
        const int cl  = t & 15;
        const int kko = (t >> 4) & 3;
        const int jq4 = t >> 6;
        const int c   = ct * 16 + cl;

        const float* yb  = y  + ((size_t)n * K_ + kko * 8) * C_ + jq4 * 128;
        const float* wvb = wv + (size_t)c * C_ + jq4 * 128;
        float acc[8] = {0,0,0,0,0,0,0,0};
        #pragma unroll 4
        for (int jj = 0; jj < 32; ++jj) {
            float4 w4 = *(const float4*)(wvb + jj * 4);
            #pragma unroll
            for (int u = 0; u < 8; ++u) {
                float4 y4 = *(const float4*)(yb + (size_t)u * C_ + jj * 4);
                acc[u] += y4.x * w4.x + y4.y * w4.y + y4.z * w4.z + y4.w * w4.w;
            }
        }
        if (jq4 > 0) {
            #pragma unroll
            for (int u = 0; u < 8; ++u) vred[jq4 - 1][kko][cl][u] = acc[u];
        }
        __syncthreads();
        if (jq4 == 0) {
            const float bvc = bv[c];
            unsigned short o[8];
            #pragma unroll
            for (int u = 0; u < 8; ++u) {
                float s = acc[u] + vred[0][kko][cl][u] + vred[1][kko][cl][u]
                        + vred[2][kko][cl][u] + bvc;
                o[u] = f2b(s);
            }
            i32x4 pk = { (int)(o[0] | ((unsigned)o[1] << 16)), (int)(o[2] | ((unsigned)o[3] << 16)),
                         (int)(o[4] | ((unsigned)o[5] << 16)), (int)(o[6] | ((unsigned)o[7] << 16)) };
            *(i32x4*)(vtf + (size_t)n * (K_ * C_) + (size_t)((ct * 64 + kko * 16 + cl) * 8)) = pk;
        }
    } else {
        // role B: krow -> bqk, wqk frags. block = (n, kk)
        __shared__ __align__(16) float kp[2][128];
        __shared__ __align__(16) float kr[128];
        const int b = bid - 256;
        const int n = b >> 5, kk = b & 31;
        const int o = t & 127, half = t >> 7;

        const float* yb  = y  + ((size_t)n * K_ + kk) * C_ + half * 256;
        const float* wkb = wk + (size_t)o * C_ + half * 256;
        float a = 0.f;
        #pragma unroll 4
        for (int jq = 0; jq < 64; ++jq) {
            float4 w4 = *(const float4*)(wkb + jq * 4);
            float4 y4 = *(const float4*)(yb + jq * 4);
            a += y4.x * w4.x + y4.y * w4.y + y4.z * w4.z + y4.w * w4.w;
        }
        kp[half][o] = a;
        __syncthreads();
        if (t < 128) kr[t] = kp[0][t] + kp[1][t] + bk[t];
        __syncthreads();
        if (t < 64) {
            float s = kr[t] * bq[t] + kr[t + 64] * bq[t + 64];
            #pragma unroll
            for (int d = 32; d > 0; d >>= 1) s += __shfl_down(s, d);
            if (t == 0) bqk[n * K_ + kk] = s;
        }
        const int c1 = t, c2 = t + 256;
        float s1 = 0.f, s2 = 0.f;
        for (int oq = 0; oq < 32; ++oq) {
            float4 k4 = *(const float4*)(&kr[oq * 4]);
            const float* wq0 = wq + (size_t)(oq * 4) * C_;
            s1 += k4.x * wq0[c1] + k4.y * wq0[C_ + c1] + k4.z * wq0[2*C_ + c1] + k4.w * wq0[3*C_ + c1];
            s2 += k4.x * wq0[c2] + k4.y * wq0[C_ + c2] + k4.z * wq0[2*C_ + c2] + k4.w * wq0[3*C_ + c2];
        }
        unsigned short* wqf_n = wqkf + (size_t)n * (K_ * C_);
        wqf_n[wqk_idx(kk, c1)] = f2b(s1);
        wqf_n[wqk_idx(kk, c2)] = f2b(s2);
    }
}

__global__ __launch_bounds__(256) void main_kernel(
    const float* __restrict__ x, const unsigned short* __restrict__ wqkf,
    const unsigned short* __restrict__ vtf, const float* __restrict__ bqk,
    const float* __restrict__ scale, float* __restrict__ out)
{
    __shared__ __align__(16) unsigned short xl[17408];   // 34 KB padded bf16 x-tile
    __shared__ float e_lds[32][33];                       // 4.2 KB

    // XCD swizzle: 128 consecutive tiles (= one image n) per XCD
    const int bid = (blockIdx.x & 7) * 128 + (blockIdx.x >> 3);
    const int n  = bid >> 7;
    const int p0 = (bid & 127) * 32;
    const int t  = threadIdx.x;
    const int w  = t >> 6, l = t & 63;
    const int l15 = l & 15, lg = l >> 4;
    const float* xg = x + (size_t)n * C_ * HW_;
    float* og = out + (size_t)n * C_ * HW_;

    // ---- Phase 0: stage x-tile -> LDS bf16 (padded subtile), 2-batch pipeline ----
    {
        const float* xp0 = xg + p0;
        const int px4 = (t & 7) * 4;           // 4 consecutive px
        const int crow = t >> 3;               // 0..31
        const int pxh = ((px4 >> 4) & 1) * 64 + (px4 & 15);
        const int crowpart = ((crow >> 3) & 3) * 272 + ((crow >> 2) & 1) * 128
                           + (crow & 3) * 16 + pxh;

        float4 ra[4], rb[4];
        #pragma unroll
        for (int u = 0; u < 4; ++u)
            ra[u] = *(const float4*)(xp0 + (size_t)(u * 32 + crow) * HW_ + px4);
        for (int b = 0; b < 4; ++b) {
            if (b < 3) {
                #pragma unroll
                for (int u = 0; u < 4; ++u)
                    rb[u] = *(const float4*)(xp0 + (size_t)((b + 1) * 128 + u * 32 + crow) * HW_ + px4);
            }
            #pragma unroll
            for (int u = 0; u < 4; ++u) {
                const float4 r = ra[u];
                const int elem = (b * 4 + u) * 1088 + crowpart;
                i32x2 pk = { (int)(f2b(r.x) | ((unsigned)f2b(r.y) << 16)),
                             (int)(f2b(r.z) | ((unsigned)f2b(r.w) << 16)) };
                *(i32x2*)(xl + elem) = pk;
            }
            #pragma unroll
            for (int u = 0; u < 4; ++u) ra[u] = rb[u];
        }
    }
    __syncthreads();

    // ---- Phase 1: energy MFMA; A from padded LDS, B-frag depth-2 prefetch ----
    {
        const int pt = w & 1, kt = w >> 1;
        const unsigned short* wqf = wqkf + (size_t)n * (K_ * C_);
        bf16x8 b0 = *(const bf16x8*)(wqf + ((size_t)(0 * 2 + kt) * 64 + l) * 8);
        bf16x8 b1 = *(const bf16x8*)(wqf + ((size_t)(1 * 2 + kt) * 64 + l) * 8);

        f32x4 acc = {0.f, 0.f, 0.f, 0.f};
        for (int cs = 0; cs < 16; ++cs) {
            bf16x8 b2;
            if (cs < 14) b2 = *(const bf16x8*)(wqf + ((size_t)((cs + 2) * 2 + kt) * 64 + l) * 8);
            const unsigned short* xp = xl + cs * 1088 + lg * 272 + pt * 64 + l15;
            const unsigned e0 = xp[0],   e1 = xp[16],  e2 = xp[32],  e3 = xp[48];
            const unsigned e4 = xp[128], e5 = xp[144], e6 = xp[160], e7 = xp[176];
            union { unsigned u[4]; bf16x8 v; } af;
            af.u[0] = e0 | (e1 << 16);  af.u[1] = e2 | (e3 << 16);
            af.u[2] = e4 | (e5 << 16);  af.u[3] = e6 | (e7 << 16);
            acc = __builtin_amdgcn_mfma_f32_16x16x32_bf16(af.v, b0, acc, 0, 0, 0);
            b0 = b1; b1 = b2;
        }
        const float bq_ = bqk[n * K_ + kt * 16 + l15];
        #pragma unroll
        for (int r = 0; r < 4; ++r)
            e_lds[pt * 16 + lg * 4 + r][kt * 16 + l15] = acc[r] + bq_;
    }
    __syncthreads();

    // ---- Phase 2: per-lane softmax for BOTH px rows (l15 and 16+l15) ----
    bf16x8 paf0, paf1;
    {
        const float* er0 = e_lds[l15];
        const float* er1 = e_lds[16 + l15];
        float e0[32], e1[32];
        #pragma unroll
        for (int k = 0; k < 32; ++k) { e0[k] = er0[k]; e1[k] = er1[k]; }
        float m0 = e0[0], m1 = e1[0];
        #pragma unroll
        for (int k = 1; k < 32; ++k) { m0 = fmaxf(m0, e0[k]); m1 = fmaxf(m1, e1[k]); }
        float s0 = 0.f, s1 = 0.f;
        #pragma unroll
        for (int k = 0; k < 32; ++k) {
            e0[k] = __expf(e0[k] - m0); s0 += e0[k];
            e1[k] = __expf(e1[k] - m1); s1 += e1[k];
        }
        const float i0 = 1.f / s0, i1 = 1.f / s1;
        #pragma unroll
        for (int j = 0; j < 8; ++j) {
            paf0[j] = (short)f2b(e0[8 * lg + j] * i0);
            paf1[j] = (short)f2b(e1[8 * lg + j] * i1);
        }
    }

    // ---- Phase 3: PV MFMA; residual from LDS (bf16); vtf depth-2; full-line writes ----
    {
        const int mh = w;                               // 0..3 -> 128 c each
        const unsigned short* vtfn = vtf + (size_t)n * (K_ * C_);
        const float fs = scale[0];
        const int pxa = p0 + l15, pxb = p0 + 16 + l15;

        const int mt0 = mh * 8;
        bf16x8 va = *(const bf16x8*)(vtfn + ((size_t)mt0 * 64 + l) * 8);
        bf16x8 vb = *(const bf16x8*)(vtfn + ((size_t)(mt0 + 1) * 64 + l) * 8);

        for (int mi = 0; mi < 8; ++mi) {
            const int mt = mt0 + mi;
            bf16x8 vc;
            if (mi < 6) vc = *(const bf16x8*)(vtfn + ((size_t)(mt + 2) * 64 + l) * 8);
            f32x4 d0 = __builtin_amdgcn_mfma_f32_16x16x32_bf16(va, paf0, (f32x4){0.f,0.f,0.f,0.f}, 0, 0, 0);
            f32x4 d1 = __builtin_amdgcn_mfma_f32_16x16x32_bf16(va, paf1, (f32x4){0.f,0.f,0.f,0.f}, 0, 0, 0);
            // residual from xl: c = mt*16 + lg*4 + r
            const int base = (mt >> 1) * 1088 + ((mt & 1) * 2 + (lg >> 1)) * 272
                           + (lg & 1) * 128 + l15;
            const int cc = mt * 16 + lg * 4;
            #pragma unroll
            for (int r = 0; r < 4; ++r) {
                const float xa0 = b2f(xl[base + r * 16]);
                const float xa1 = b2f(xl[base + r * 16 + 64]);
                og[(size_t)(cc + r) * HW_ + pxa] = fs * d0[r] + xa0;
                og[(size_t)(cc + r) * HW_ + pxb] = fs * d1[r] + xa1;
            }
            va = vb; vb = vc;
        }
    }
}

extern "C" void kernel_launch(void* const* d_in, const int* in_sizes, int n_in,
                              void* d_out, int out_size, void* d_ws, size_t ws_size,
                              hipStream_t stream) {
    const float* x     = (const float*)d_in[0];
    const float* y     = (const float*)d_in[1];
    const float* wq    = (const float*)d_in[2];
    const float* bq    = (const float*)d_in[3];
    const float* wk    = (const float*)d_in[4];
    const float* bk    = (const float*)d_in[5];
    const float* wv    = (const float*)d_in[6];
    const float* bv    = (const float*)d_in[7];
    const float* scale = (const float*)d_in[8];

    unsigned short* wqkf = (unsigned short*)d_ws;                       // 256 KB
    unsigned short* vtf  = wqkf + (size_t)N_ * K_ * C_;                 // 256 KB
    float* bqk = (float*)((char*)d_ws + 524288);                        // 1 KB

    prep_kernel<<<512, 256, 0, stream>>>(y, wq, bq, wk, bk, wv, bv, wqkf, bqk, vtf);
    main_kernel<<<1024, 256, 0, stream>>>(x, wqkf, vtf, bqk, scale, (float*)d_out);
}